// Round 4
// baseline (86.512 us; speedup 1.0000x reference)
//
#include <hip/hip_runtime.h>

// Diversity5: out = mean_b( SCALE * sum_{i<j} corr(v_i[b], v_j[b]) )
// v_m = normalize(center(softmax(outputs_m / T))).
// Identities:
//   mean_c(softmax) == 1/C                      (softmax sums to 1)
//   sum_{i<j} v_i.v_j == (||sum_m v_m||^2-M)/2  (unit-norm v_m)
// R3 restructure: one 256-thread BLOCK per row (was one wave per row).
// Each thread owns one float4 per model -> 5 loads, ~20 live floats,
// VGPR stays low -> 8 waves/SIMD occupancy and 4x shorter serial chain
// per row. Cross-wave reduction via 176 B of LDS, 3 barriers per row.

#define CDIM   1000
#define C4DIM  250
#define NMODEL 5
#define T_INV  (1.0f / 20.0f)
#define INV_C  (1.0f / 1000.0f)
#define SCALEF 0.3f

__global__ __launch_bounds__(256) void diversity_rows(
    const float* __restrict__ o1, const float* __restrict__ o2,
    const float* __restrict__ o3, const float* __restrict__ o4,
    const float* __restrict__ o5, float* __restrict__ ws)
{
    const int b    = blockIdx.x;
    const int t    = threadIdx.x;          // 0..255
    const int wv   = t >> 6;               // wave id 0..3
    const int lane = t & 63;
    const bool act = t < C4DIM;             // 250 float4s per row
    const int idx  = act ? t : 0;           // clamp (avoid OOB on last row)

    __shared__ float redA[4][NMODEL];       // round 1: sum(e)
    __shared__ float redB[4][NMODEL];       // round 2: sum(v*v)
    __shared__ float redC[4];               // round 3: sum(s*s)

    const size_t roff = (size_t)b * CDIM;

    // ---------- phase 0: 5 loads (one float4 per model) ----------
    float e[NMODEL][4];
    {
        const float4* p[NMODEL] = {
            reinterpret_cast<const float4*>(o1 + roff),
            reinterpret_cast<const float4*>(o2 + roff),
            reinterpret_cast<const float4*>(o3 + roff),
            reinterpret_cast<const float4*>(o4 + roff),
            reinterpret_cast<const float4*>(o5 + roff)};
        #pragma unroll
        for (int m = 0; m < NMODEL; ++m) {
            float4 v = p[m][idx];
            e[m][0] = v.x; e[m][1] = v.y; e[m][2] = v.z; e[m][3] = v.w;
        }
    }
    __builtin_amdgcn_sched_barrier(0);      // pin: all 5 loads issued first

    // ---------- phase 1: exp (no max: |x/T| <= ~0.3) + block sum(e) ----------
    float lsum[NMODEL];
    #pragma unroll
    for (int m = 0; m < NMODEL; ++m) {
        float a = 0.0f;
        #pragma unroll
        for (int j = 0; j < 4; ++j) {
            float ev = act ? __expf(e[m][j] * T_INV) : 0.0f;
            e[m][j] = ev;
            a += ev;
        }
        lsum[m] = a;
    }
    #pragma unroll
    for (int off = 32; off >= 1; off >>= 1) {
        #pragma unroll
        for (int m = 0; m < NMODEL; ++m)
            lsum[m] += __shfl_xor(lsum[m], off);
    }
    if (lane == 0) {
        #pragma unroll
        for (int m = 0; m < NMODEL; ++m) redA[wv][m] = lsum[m];
    }
    __syncthreads();

    float rS[NMODEL];
    #pragma unroll
    for (int m = 0; m < NMODEL; ++m)
        rS[m] = 1.0f / (redA[0][m] + redA[1][m] + redA[2][m] + redA[3][m]);

    // ---------- phase 2: v = p - 1/C (exact mean); block sum(v*v) ----------
    float lss[NMODEL];
    #pragma unroll
    for (int m = 0; m < NMODEL; ++m) {
        float a = 0.0f;
        #pragma unroll
        for (int j = 0; j < 4; ++j) {
            float v = act ? (e[m][j] * rS[m] - INV_C) : 0.0f;
            e[m][j] = v;
            a += v * v;
        }
        lss[m] = a;
    }
    #pragma unroll
    for (int off = 32; off >= 1; off >>= 1) {
        #pragma unroll
        for (int m = 0; m < NMODEL; ++m)
            lss[m] += __shfl_xor(lss[m], off);
    }
    if (lane == 0) {
        #pragma unroll
        for (int m = 0; m < NMODEL; ++m) redB[wv][m] = lss[m];
    }
    __syncthreads();

    float rn[NMODEL];
    #pragma unroll
    for (int m = 0; m < NMODEL; ++m)
        rn[m] = 1.0f / sqrtf(redB[0][m] + redB[1][m] + redB[2][m] + redB[3][m]);

    // ---------- phase 3: s = sum_m v_m/||v_m||; block sum(s*s) ----------
    float ssl = 0.0f;
    #pragma unroll
    for (int j = 0; j < 4; ++j) {
        float si = e[0][j] * rn[0];
        #pragma unroll
        for (int m = 1; m < NMODEL; ++m) si += e[m][j] * rn[m];
        ssl += si * si;
    }
    #pragma unroll
    for (int off = 32; off >= 1; off >>= 1)
        ssl += __shfl_xor(ssl, off);
    if (lane == 0) redC[wv] = ssl;
    __syncthreads();

    if (t == 0) {
        float ss = redC[0] + redC[1] + redC[2] + redC[3];
        ws[b] = SCALEF * 0.5f * (ss - (float)NMODEL);
    }
}

// Deterministic fixed-order reduction of B partials -> mean, in double.
__global__ __launch_bounds__(1024) void final_reduce(
    const float* __restrict__ ws, float* __restrict__ out, int B)
{
    __shared__ double sm[1024];
    double acc = 0.0;
    for (int i = threadIdx.x; i < B; i += 1024)
        acc += (double)ws[i];
    sm[threadIdx.x] = acc;
    __syncthreads();
    #pragma unroll
    for (int s = 512; s > 0; s >>= 1) {
        if (threadIdx.x < s) sm[threadIdx.x] += sm[threadIdx.x + s];
        __syncthreads();
    }
    if (threadIdx.x == 0)
        out[0] = (float)(sm[0] / (double)B);
}

extern "C" void kernel_launch(void* const* d_in, const int* in_sizes, int n_in,
                              void* d_out, int out_size, void* d_ws, size_t ws_size,
                              hipStream_t stream)
{
    const float* o1 = (const float*)d_in[0];
    const float* o2 = (const float*)d_in[1];
    const float* o3 = (const float*)d_in[2];
    const float* o4 = (const float*)d_in[3];
    const float* o5 = (const float*)d_in[4];
    // d_in[5] (targets) unused by the reference.

    float* ws  = (float*)d_ws;
    float* out = (float*)d_out;

    const int B = in_sizes[0] / CDIM;   // 16384

    diversity_rows<<<B, 256, 0, stream>>>(o1, o2, o3, o4, o5, ws);
    final_reduce<<<1, 1024, 0, stream>>>(ws, out, B);
}

// Round 5
// 72.019 us; speedup vs baseline: 1.2012x; 1.2012x over previous
//
#include <hip/hip_runtime.h>

// Diversity5: out = mean_b( SCALE * sum_{i<j} corr(v_i[b], v_j[b]) ),
// v_m = normalize(center(softmax(outputs_m / T))).
//
// R4 reformulation (one-pass, barrier-free): with u = exp(x/T) - 1,
//   A_m = sum_c u_m,  B_ij = sum_c u_i u_j   (i<=j, 15 pairs)
//   corr_ij = (C*B_ij - A_i*A_j) / sqrt((C*B_ii - A_i^2)(C*B_jj - A_j^2))
// (the C(C+A_i)(C+A_j) factors cancel between numerator and the norms).
// => each wave streams its row once, accumulates 20 registers, does ONE
// 64-lane butterfly, computes d, writes ws[b]. No LDS, no __syncthreads.
// Masked tail elements load 0 -> u = exp(0)-1 = 0 -> contribute nothing.

#define CDIM   1000
#define C4DIM  250
#define NM     5
#define NP     15
#define T_INV  (1.0f / 20.0f)
#define SCALEF 0.3f

__global__ __launch_bounds__(256) void diversity_rows(
    const float* __restrict__ o1, const float* __restrict__ o2,
    const float* __restrict__ o3, const float* __restrict__ o4,
    const float* __restrict__ o5, float* __restrict__ ws, int B)
{
    const int lane = threadIdx.x & 63;
    const int wid  = threadIdx.x >> 6;
    const int b    = blockIdx.x * 4 + wid;
    if (b >= B) return;

    const bool act3 = lane < (C4DIM - 192);   // slot 3 partial (250 float4/row)
    const size_t roff = (size_t)b * CDIM;
    const float4* base[NM] = {
        reinterpret_cast<const float4*>(o1 + roff),
        reinterpret_cast<const float4*>(o2 + roff),
        reinterpret_cast<const float4*>(o3 + roff),
        reinterpret_cast<const float4*>(o4 + roff),
        reinterpret_cast<const float4*>(o5 + roff)};

    float A[NM];
    float Bv[NP];
    #pragma unroll
    for (int i = 0; i < NM; ++i) A[i] = 0.0f;
    #pragma unroll
    for (int p = 0; p < NP; ++p) Bv[p] = 0.0f;

    float4 xb[2][NM];   // double-buffered slot loads (all indices static)

    // prologue: issue slot-0 loads
    #pragma unroll
    for (int m = 0; m < NM; ++m)
        xb[0][m] = base[m][lane];

    #pragma unroll
    for (int k = 0; k < 4; ++k) {
        const int cur = k & 1;
        const int nxt = cur ^ 1;

        // prefetch slot k+1 before computing slot k
        if (k + 1 < 4) {
            if (k + 1 == 3) {
                #pragma unroll
                for (int m = 0; m < NM; ++m) {
                    float4 t = make_float4(0.0f, 0.0f, 0.0f, 0.0f);
                    if (act3) t = base[m][lane + 192];
                    xb[nxt][m] = t;
                }
            } else {
                #pragma unroll
                for (int m = 0; m < NM; ++m)
                    xb[nxt][m] = base[m][lane + 64 * (k + 1)];
            }
        }
        __builtin_amdgcn_sched_barrier(0);   // loads issued before compute

        // compute slot k: u = exp(x/T) - 1, accumulate A and B
        float u[NM][4];
        #pragma unroll
        for (int m = 0; m < NM; ++m) {
            float4 v = xb[cur][m];
            u[m][0] = __expf(v.x * T_INV) - 1.0f;
            u[m][1] = __expf(v.y * T_INV) - 1.0f;
            u[m][2] = __expf(v.z * T_INV) - 1.0f;
            u[m][3] = __expf(v.w * T_INV) - 1.0f;
        }
        #pragma unroll
        for (int c = 0; c < 4; ++c) {
            #pragma unroll
            for (int i = 0; i < NM; ++i) A[i] += u[i][c];
            int p = 0;
            #pragma unroll
            for (int i = 0; i < NM; ++i) {
                #pragma unroll
                for (int j = i; j < NM; ++j) {
                    Bv[p] = fmaf(u[i][c], u[j][c], Bv[p]);
                    ++p;
                }
            }
        }
    }

    // single butterfly: 20 interleaved chains, 6 steps
    #pragma unroll
    for (int off = 32; off >= 1; off >>= 1) {
        #pragma unroll
        for (int i = 0; i < NM; ++i) A[i] += __shfl_xor(A[i], off);
        #pragma unroll
        for (int p = 0; p < NP; ++p) Bv[p] += __shfl_xor(Bv[p], off);
    }

    // d = sum_{i<j} corr_ij (all lanes redundantly, lane 0 stores)
    {
        const double Cd = (double)CDIM;
        double Ad[NM], den[NM];
        #pragma unroll
        for (int i = 0; i < NM; ++i) Ad[i] = (double)A[i];
        const int diag[NM] = {0, 5, 9, 12, 14};
        #pragma unroll
        for (int i = 0; i < NM; ++i)
            den[i] = sqrt(Cd * (double)Bv[diag[i]] - Ad[i] * Ad[i]);

        double d = 0.0;
        int p = 0;
        #pragma unroll
        for (int i = 0; i < NM; ++i) {
            #pragma unroll
            for (int j = i; j < NM; ++j) {
                if (j > i)
                    d += (Cd * (double)Bv[p] - Ad[i] * Ad[j]) / (den[i] * den[j]);
                ++p;
            }
        }
        if (lane == 0)
            ws[b] = (float)((double)SCALEF * d);
    }
}

// Deterministic fixed-order reduction of B partials -> mean, in double.
__global__ __launch_bounds__(1024) void final_reduce(
    const float* __restrict__ ws, float* __restrict__ out, int B)
{
    __shared__ double sm[1024];
    double acc = 0.0;
    for (int i = threadIdx.x; i < B; i += 1024)
        acc += (double)ws[i];
    sm[threadIdx.x] = acc;
    __syncthreads();
    #pragma unroll
    for (int s = 512; s > 0; s >>= 1) {
        if (threadIdx.x < s) sm[threadIdx.x] += sm[threadIdx.x + s];
        __syncthreads();
    }
    if (threadIdx.x == 0)
        out[0] = (float)(sm[0] / (double)B);
}

extern "C" void kernel_launch(void* const* d_in, const int* in_sizes, int n_in,
                              void* d_out, int out_size, void* d_ws, size_t ws_size,
                              hipStream_t stream)
{
    const float* o1 = (const float*)d_in[0];
    const float* o2 = (const float*)d_in[1];
    const float* o3 = (const float*)d_in[2];
    const float* o4 = (const float*)d_in[3];
    const float* o5 = (const float*)d_in[4];
    // d_in[5] (targets) unused by the reference.

    float* ws  = (float*)d_ws;
    float* out = (float*)d_out;

    const int B = in_sizes[0] / CDIM;   // 16384

    diversity_rows<<<(B + 3) / 4, 256, 0, stream>>>(o1, o2, o3, o4, o5, ws, B);
    final_reduce<<<1, 1024, 0, stream>>>(ws, out, B);
}

// Round 6
// 64.288 us; speedup vs baseline: 1.3457x; 1.1202x over previous
//
#include <hip/hip_runtime.h>

// Diversity5: out = mean_b( SCALE * sum_{i<j} corr(v_i[b], v_j[b]) ),
// v_m = normalize(center(softmax(outputs_m / T))).
//
// One-pass reformulation (R4, kept): with u = exp(x/T) - 1,
//   A_m = sum_c u_m,  B_ij = sum_c u_i u_j  (i<=j, 15 pairs)
//   corr_ij = (C*B_ij - A_i*A_j) * rsqrt(C*B_ii - A_i^2) * rsqrt(C*B_jj - A_j^2)
// R5: manual VMEM pipeline. The compiler kept sinking prefetches (VGPR=52),
// capping in-flight loads at ~5/wave -> latency-bound at 4.5 TB/s combined.
// Now all 20 global_load_dwordx4 are issued via inline asm (unsinkable),
// consumed behind counted s_waitcnt vmcnt(15/10/5/0) + sched_barrier(0)
// (rule #18). No LDS, no __syncthreads in the hot kernel.

typedef float f32x4 __attribute__((ext_vector_type(4)));

#define CDIM   1000
#define C4DIM  250
#define NM     5
#define NP     15
#define T_INV  (1.0f / 20.0f)
#define SCALEF 0.3f

#define GLOAD(dst, p) \
    asm volatile("global_load_dwordx4 %0, %1, off" : "=v"(dst) : "v"(p) : "memory")

#define WAITVM(N)                                              \
    asm volatile("s_waitcnt vmcnt(" #N ")" ::: "memory");      \
    __builtin_amdgcn_sched_barrier(0)

template <bool MASKED>
__device__ __forceinline__ void slot_accum(const f32x4* xs, bool act,
                                           float* A, float* Bv)
{
    float u[NM][4];
    #pragma unroll
    for (int m = 0; m < NM; ++m) {
        #pragma unroll
        for (int c = 0; c < 4; ++c) {
            float xv = xs[m][c];
            if (MASKED) xv = act ? xv : 0.0f;   // exp(0)-1 == 0 exactly
            u[m][c] = __expf(xv * T_INV) - 1.0f;
        }
    }
    #pragma unroll
    for (int c = 0; c < 4; ++c) {
        #pragma unroll
        for (int i = 0; i < NM; ++i) A[i] += u[i][c];
        int p = 0;
        #pragma unroll
        for (int i = 0; i < NM; ++i) {
            #pragma unroll
            for (int j = i; j < NM; ++j) {
                Bv[p] = fmaf(u[i][c], u[j][c], Bv[p]);
                ++p;
            }
        }
    }
}

__global__ __launch_bounds__(256) void diversity_rows(
    const float* __restrict__ o1, const float* __restrict__ o2,
    const float* __restrict__ o3, const float* __restrict__ o4,
    const float* __restrict__ o5, float* __restrict__ ws, int B)
{
    const int lane = threadIdx.x & 63;
    const int wid  = threadIdx.x >> 6;
    const int b    = blockIdx.x * 4 + wid;
    if (b >= B) return;

    const bool act3 = (lane + 192) < C4DIM;            // 250 float4/row
    const int  i3   = act3 ? (lane + 192) : (C4DIM - 1); // clamp: never OOB

    const size_t roff = (size_t)b * CDIM;
    const float* rp[NM] = {o1 + roff, o2 + roff, o3 + roff, o4 + roff, o5 + roff};

    // ---- issue ALL 20 loads, slot-major (consumption order) ----
    f32x4 x0[NM], x1[NM], x2[NM], x3[NM];
    #pragma unroll
    for (int m = 0; m < NM; ++m) GLOAD(x0[m], rp[m] + (size_t)lane * 4);
    #pragma unroll
    for (int m = 0; m < NM; ++m) GLOAD(x1[m], rp[m] + (size_t)(lane + 64) * 4);
    #pragma unroll
    for (int m = 0; m < NM; ++m) GLOAD(x2[m], rp[m] + (size_t)(lane + 128) * 4);
    #pragma unroll
    for (int m = 0; m < NM; ++m) GLOAD(x3[m], rp[m] + (size_t)i3 * 4);

    float A[NM], Bv[NP];
    #pragma unroll
    for (int i = 0; i < NM; ++i) A[i] = 0.0f;
    #pragma unroll
    for (int p = 0; p < NP; ++p) Bv[p] = 0.0f;

    // ---- consume behind counted vmcnt (20 outstanding at start) ----
    WAITVM(15);  slot_accum<false>(x0, true, A, Bv);
    WAITVM(10);  slot_accum<false>(x1, true, A, Bv);
    WAITVM(5);   slot_accum<false>(x2, true, A, Bv);
    WAITVM(0);   slot_accum<true >(x3, act3, A, Bv);

    // ---- single butterfly: 20 interleaved chains, 6 steps ----
    #pragma unroll
    for (int off = 32; off >= 1; off >>= 1) {
        #pragma unroll
        for (int i = 0; i < NM; ++i) A[i] += __shfl_xor(A[i], off);
        #pragma unroll
        for (int p = 0; p < NP; ++p) Bv[p] += __shfl_xor(Bv[p], off);
    }

    // ---- d = sum_{i<j} corr_ij, fp32 epilogue ----
    {
        const float Cf = (float)CDIM;
        const int diag[NM] = {0, 5, 9, 12, 14};
        float rden[NM];
        #pragma unroll
        for (int i = 0; i < NM; ++i)
            rden[i] = rsqrtf(fmaf(Cf, Bv[diag[i]], -A[i] * A[i]));

        float d = 0.0f;
        int p = 0;
        #pragma unroll
        for (int i = 0; i < NM; ++i) {
            #pragma unroll
            for (int j = i; j < NM; ++j) {
                if (j > i)
                    d += fmaf(Cf, Bv[p], -A[i] * A[j]) * rden[i] * rden[j];
                ++p;
            }
        }
        if (lane == 0)
            ws[b] = SCALEF * d;
    }
}

// Deterministic fixed-order reduction of B partials -> mean, in double.
__global__ __launch_bounds__(1024) void final_reduce(
    const float* __restrict__ ws, float* __restrict__ out, int B)
{
    __shared__ double sm[1024];
    double acc = 0.0;
    for (int i = threadIdx.x; i < B; i += 1024)
        acc += (double)ws[i];
    sm[threadIdx.x] = acc;
    __syncthreads();
    #pragma unroll
    for (int s = 512; s > 0; s >>= 1) {
        if (threadIdx.x < s) sm[threadIdx.x] += sm[threadIdx.x + s];
        __syncthreads();
    }
    if (threadIdx.x == 0)
        out[0] = (float)(sm[0] / (double)B);
}

extern "C" void kernel_launch(void* const* d_in, const int* in_sizes, int n_in,
                              void* d_out, int out_size, void* d_ws, size_t ws_size,
                              hipStream_t stream)
{
    const float* o1 = (const float*)d_in[0];
    const float* o2 = (const float*)d_in[1];
    const float* o3 = (const float*)d_in[2];
    const float* o4 = (const float*)d_in[3];
    const float* o5 = (const float*)d_in[4];
    // d_in[5] (targets) unused by the reference.

    float* ws  = (float*)d_ws;
    float* out = (float*)d_out;

    const int B = in_sizes[0] / CDIM;   // 16384

    diversity_rows<<<(B + 3) / 4, 256, 0, stream>>>(o1, o2, o3, o4, o5, ws, B);
    final_reduce<<<1, 1024, 0, stream>>>(ws, out, B);
}

// Round 9
// 63.444 us; speedup vs baseline: 1.3636x; 1.0133x over previous
//
#include <hip/hip_runtime.h>

// Diversity5: out = mean_b( SCALE * sum_{i<j} corr(v_i[b], v_j[b]) ),
// v_m = normalize(center(softmax(outputs_m / T))).
//
// One-pass reformulation (R4): with u = exp(x/T) - 1,
//   A_m = sum_c u_m,  B_ij = sum_c u_i u_j  (i<=j, 15 pairs)
//   corr_ij = (C*B_ij - A_i*A_j) * rsqrt(C*B_ii - A_i^2) * rsqrt(C*B_jj - A_j^2)
// R5/R6 (proven): 20 inline-asm global_load_dwordx4 per row, consumed behind
//   counted s_waitcnt vmcnt(15/10/5/0) + sched_barrier(0) (rule #18).
// R7/R8 (failed): keeping those 20 dests live ACROSS the butterfly/epilogue
//   spilled -> vmcnt corruption (NaN), then abort. Lesson: asm-load dests
//   must die before any register-hungry region.
// R9: persistent waves, ROWS=4 rows each, ONE-SHOT per row (issue->wait->
//   consume->reduce; no cross-row in-flight state). 1024 blocks instead of
//   4096 kills block churn; TLP hides per-row drain. Per-block partial sum
//   (fixed order) -> ws[1024]; final_reduce reads 4 KB.

typedef float f32x4 __attribute__((ext_vector_type(4)));

#define CDIM   1000
#define C4DIM  250
#define NM     5
#define NP     15
#define ROWS   4
#define T_INV  (1.0f / 20.0f)
#define SCALEF 0.3f

#define GLOAD(dst, p) \
    asm volatile("global_load_dwordx4 %0, %1, off" : "=v"(dst) : "v"(p) : "memory")

#define WAITVM(N)                                              \
    asm volatile("s_waitcnt vmcnt(" #N ")" ::: "memory");      \
    __builtin_amdgcn_sched_barrier(0)

// Issue one row's 20 loads in slot-major order (vmcnt retire order must
// match consumption order: all x0s, then x1s, x2s, x3s).
__device__ __forceinline__ void issue_row(const float* const* rp, int lane, int i3,
                                          f32x4* x0, f32x4* x1, f32x4* x2, f32x4* x3)
{
    #pragma unroll
    for (int m = 0; m < NM; ++m) GLOAD(x0[m], rp[m] + (size_t)lane * 4);
    #pragma unroll
    for (int m = 0; m < NM; ++m) GLOAD(x1[m], rp[m] + (size_t)(lane + 64) * 4);
    #pragma unroll
    for (int m = 0; m < NM; ++m) GLOAD(x2[m], rp[m] + (size_t)(lane + 128) * 4);
    #pragma unroll
    for (int m = 0; m < NM; ++m) GLOAD(x3[m], rp[m] + (size_t)i3 * 4);
}

template <bool MASKED>
__device__ __forceinline__ void slot_accum(const f32x4* xs, bool act,
                                           float* A, float* Bv)
{
    float u[NM][4];
    #pragma unroll
    for (int m = 0; m < NM; ++m) {
        #pragma unroll
        for (int c = 0; c < 4; ++c) {
            float xv = xs[m][c];
            if (MASKED) xv = act ? xv : 0.0f;   // exp(0)-1 == 0 exactly
            u[m][c] = __expf(xv * T_INV) - 1.0f;
        }
    }
    #pragma unroll
    for (int c = 0; c < 4; ++c) {
        #pragma unroll
        for (int i = 0; i < NM; ++i) A[i] += u[i][c];
        int p = 0;
        #pragma unroll
        for (int i = 0; i < NM; ++i) {
            #pragma unroll
            for (int j = i; j < NM; ++j) {
                Bv[p] = fmaf(u[i][c], u[j][c], Bv[p]);
                ++p;
            }
        }
    }
}

__global__ __launch_bounds__(256) void diversity_rows(
    const float* __restrict__ o1, const float* __restrict__ o2,
    const float* __restrict__ o3, const float* __restrict__ o4,
    const float* __restrict__ o5, float* __restrict__ ws, int B)
{
    const int lane = threadIdx.x & 63;
    const int wid  = threadIdx.x >> 6;
    const int b0   = (blockIdx.x * 4 + wid) * ROWS;   // first row of this wave

    __shared__ float sm4[4];

    const bool act3 = (lane + 192) < C4DIM;              // 250 float4/row
    const int  i3   = act3 ? (lane + 192) : (C4DIM - 1); // clamp: never OOB

    float dsum = 0.0f;

    if (b0 < B) {
        const float* rp[NM] = {
            o1 + (size_t)b0 * CDIM, o2 + (size_t)b0 * CDIM, o3 + (size_t)b0 * CDIM,
            o4 + (size_t)b0 * CDIM, o5 + (size_t)b0 * CDIM};

        #pragma unroll 1
        for (int r = 0; r < ROWS; ++r) {
            f32x4 x0[NM], x1[NM], x2[NM], x3[NM];
            issue_row(rp, lane, i3, x0, x1, x2, x3);

            float A[NM], Bv[NP];
            #pragma unroll
            for (int i = 0; i < NM; ++i) A[i] = 0.0f;
            #pragma unroll
            for (int p = 0; p < NP; ++p) Bv[p] = 0.0f;

            // consume behind counted vmcnt (20 outstanding after issue)
            WAITVM(15);  slot_accum<false>(x0, true, A, Bv);
            WAITVM(10);  slot_accum<false>(x1, true, A, Bv);
            WAITVM(5);   slot_accum<false>(x2, true, A, Bv);
            WAITVM(0);   slot_accum<true >(x3, act3, A, Bv);
            __builtin_amdgcn_sched_barrier(0);

            // butterfly: 20 interleaved chains, 6 steps (asm state all dead)
            #pragma unroll
            for (int off = 32; off >= 1; off >>= 1) {
                #pragma unroll
                for (int i = 0; i < NM; ++i) A[i] += __shfl_xor(A[i], off);
                #pragma unroll
                for (int p = 0; p < NP; ++p) Bv[p] += __shfl_xor(Bv[p], off);
            }

            // d = sum_{i<j} corr_ij, fp32 epilogue (all lanes redundantly)
            {
                const float Cf = (float)CDIM;
                const int diag[NM] = {0, 5, 9, 12, 14};
                float rden[NM];
                #pragma unroll
                for (int i = 0; i < NM; ++i)
                    rden[i] = rsqrtf(fmaf(Cf, Bv[diag[i]], -A[i] * A[i]));

                float d = 0.0f;
                int p = 0;
                #pragma unroll
                for (int i = 0; i < NM; ++i) {
                    #pragma unroll
                    for (int j = i; j < NM; ++j) {
                        if (j > i)
                            d += fmaf(Cf, Bv[p], -A[i] * A[j]) * rden[i] * rden[j];
                        ++p;
                    }
                }
                dsum += SCALEF * d;
            }

            #pragma unroll
            for (int m = 0; m < NM; ++m) rp[m] += CDIM;
        }
    }

    // per-block partial (fixed order): 4 waves -> 1 float
    if (lane == 0) sm4[wid] = dsum;
    __syncthreads();
    if (threadIdx.x == 0)
        ws[blockIdx.x] = (sm4[0] + sm4[1]) + (sm4[2] + sm4[3]);
}

// Deterministic fixed-order reduction of nblk block partials -> mean over B.
__global__ __launch_bounds__(256) void final_reduce(
    const float* __restrict__ ws, float* __restrict__ out, int nblk, int B)
{
    __shared__ double sm[256];
    double acc = 0.0;
    for (int i = threadIdx.x; i < nblk; i += 256)
        acc += (double)ws[i];
    sm[threadIdx.x] = acc;
    __syncthreads();
    #pragma unroll
    for (int s = 128; s > 0; s >>= 1) {
        if (threadIdx.x < s) sm[threadIdx.x] += sm[threadIdx.x + s];
        __syncthreads();
    }
    if (threadIdx.x == 0)
        out[0] = (float)(sm[0] / (double)B);
}

extern "C" void kernel_launch(void* const* d_in, const int* in_sizes, int n_in,
                              void* d_out, int out_size, void* d_ws, size_t ws_size,
                              hipStream_t stream)
{
    const float* o1 = (const float*)d_in[0];
    const float* o2 = (const float*)d_in[1];
    const float* o3 = (const float*)d_in[2];
    const float* o4 = (const float*)d_in[3];
    const float* o5 = (const float*)d_in[4];
    // d_in[5] (targets) unused by the reference.

    float* ws  = (float*)d_ws;
    float* out = (float*)d_out;

    const int B = in_sizes[0] / CDIM;                 // 16384
    const int waves  = (B + ROWS - 1) / ROWS;         // 4096
    const int blocks = (waves + 3) / 4;               // 1024

    diversity_rows<<<blocks, 256, 0, stream>>>(o1, o2, o3, o4, o5, ws, B);
    final_reduce<<<1, 256, 0, stream>>>(ws, out, blocks, B);
}

// Round 11
// 61.931 us; speedup vs baseline: 1.3969x; 1.0244x over previous
//
#include <hip/hip_runtime.h>

// Diversity5: out = mean_b( SCALE * sum_{i<j} corr(v_i[b], v_j[b]) ),
// v_m = normalize(center(softmax(outputs_m / T))).
//
// One-pass reformulation (R4): with u = exp(x/T) - 1,
//   A_m = sum_c u_m,  B_ij = sum_c u_i u_j  (i<=j, 15 pairs)
//   corr_ij = (C*B_ij - A_i*A_j) * rsqrt(C*B_ii - A_i^2) * rsqrt(C*B_jj - A_j^2)
// R9 (proven, absmax 0): persistent waves, 4 rows each, ONE-SHOT per row:
//   20 inline-asm global_load_dwordx4 -> counted vmcnt(15/10/5/0) consume
//   (+ sched_barrier(0), rule #18) -> butterfly -> epilogue. No asm-load
//   dest survives into any compiler-scheduled region.
// R7/R8/R10 lesson (3 failures): ANY cross-row in-flight asm destination
//   (spilled or loop-carried/PHI-copied) reads stale registers -> corrupt.
//   Do not prefetch into registers across the reduction at HIP level.
// R11: de-correlate the per-row drains instead. All resident waves run the
//   same code from the same start -> their WAITVM(0)+reduce phases align and
//   the whole CU's VMEM queue empties once per row (~10% of row period).
//   One-time per-block s_sleep stagger (0/256/512/768 cyc by presumed
//   co-residency group, blockIdx>>8) breaks the lockstep at ~0 cost.

typedef float f32x4 __attribute__((ext_vector_type(4)));

#define CDIM   1000
#define C4DIM  250
#define NM     5
#define NP     15
#define ROWS   4
#define T_INV  (1.0f / 20.0f)
#define SCALEF 0.3f

#define GLOAD(dst, p) \
    asm volatile("global_load_dwordx4 %0, %1, off" : "=v"(dst) : "v"(p) : "memory")

#define WAITVM(N)                                              \
    asm volatile("s_waitcnt vmcnt(" #N ")" ::: "memory");      \
    __builtin_amdgcn_sched_barrier(0)

// Issue one row's 20 loads in slot-major order (vmcnt retire order must
// match consumption order: all x0s, then x1s, x2s, x3s).
__device__ __forceinline__ void issue_row(const float* const* rp, int lane, int i3,
                                          f32x4* x0, f32x4* x1, f32x4* x2, f32x4* x3)
{
    #pragma unroll
    for (int m = 0; m < NM; ++m) GLOAD(x0[m], rp[m] + (size_t)lane * 4);
    #pragma unroll
    for (int m = 0; m < NM; ++m) GLOAD(x1[m], rp[m] + (size_t)(lane + 64) * 4);
    #pragma unroll
    for (int m = 0; m < NM; ++m) GLOAD(x2[m], rp[m] + (size_t)(lane + 128) * 4);
    #pragma unroll
    for (int m = 0; m < NM; ++m) GLOAD(x3[m], rp[m] + (size_t)i3 * 4);
}

template <bool MASKED>
__device__ __forceinline__ void slot_accum(const f32x4* xs, bool act,
                                           float* A, float* Bv)
{
    float u[NM][4];
    #pragma unroll
    for (int m = 0; m < NM; ++m) {
        #pragma unroll
        for (int c = 0; c < 4; ++c) {
            float xv = xs[m][c];
            if (MASKED) xv = act ? xv : 0.0f;   // exp(0)-1 == 0 exactly
            u[m][c] = __expf(xv * T_INV) - 1.0f;
        }
    }
    #pragma unroll
    for (int c = 0; c < 4; ++c) {
        #pragma unroll
        for (int i = 0; i < NM; ++i) A[i] += u[i][c];
        int p = 0;
        #pragma unroll
        for (int i = 0; i < NM; ++i) {
            #pragma unroll
            for (int j = i; j < NM; ++j) {
                Bv[p] = fmaf(u[i][c], u[j][c], Bv[p]);
                ++p;
            }
        }
    }
}

__global__ __launch_bounds__(256) void diversity_rows(
    const float* __restrict__ o1, const float* __restrict__ o2,
    const float* __restrict__ o3, const float* __restrict__ o4,
    const float* __restrict__ o5, float* __restrict__ ws, int B)
{
    const int lane = threadIdx.x & 63;
    const int wid  = threadIdx.x >> 6;
    const int b0   = (blockIdx.x * 4 + wid) * ROWS;   // first row of this wave

    __shared__ float sm4[4];

    // One-time phase stagger: co-resident blocks (likely blockIdx differing
    // by 256 with 1024 blocks on 256 CUs) get 0/256/512/768-cycle offsets so
    // their per-row drain+reduce phases don't align on a SIMD.
    {
        const int stag = (blockIdx.x >> 8) & 3;
        for (int i = 0; i < stag; ++i)
            __builtin_amdgcn_s_sleep(4);     // 4*64 = 256 cycles each
    }

    const bool act3 = (lane + 192) < C4DIM;              // 250 float4/row
    const int  i3   = act3 ? (lane + 192) : (C4DIM - 1); // clamp: never OOB

    float dsum = 0.0f;

    if (b0 < B) {
        const float* rp[NM] = {
            o1 + (size_t)b0 * CDIM, o2 + (size_t)b0 * CDIM, o3 + (size_t)b0 * CDIM,
            o4 + (size_t)b0 * CDIM, o5 + (size_t)b0 * CDIM};

        #pragma unroll 1
        for (int r = 0; r < ROWS; ++r) {
            f32x4 x0[NM], x1[NM], x2[NM], x3[NM];
            issue_row(rp, lane, i3, x0, x1, x2, x3);

            float A[NM], Bv[NP];
            #pragma unroll
            for (int i = 0; i < NM; ++i) A[i] = 0.0f;
            #pragma unroll
            for (int p = 0; p < NP; ++p) Bv[p] = 0.0f;

            // consume behind counted vmcnt (20 outstanding after issue)
            WAITVM(15);  slot_accum<false>(x0, true, A, Bv);
            WAITVM(10);  slot_accum<false>(x1, true, A, Bv);
            WAITVM(5);   slot_accum<false>(x2, true, A, Bv);
            WAITVM(0);   slot_accum<true >(x3, act3, A, Bv);
            __builtin_amdgcn_sched_barrier(0);

            // butterfly: 20 interleaved chains, 6 steps (asm state all dead)
            #pragma unroll
            for (int off = 32; off >= 1; off >>= 1) {
                #pragma unroll
                for (int i = 0; i < NM; ++i) A[i] += __shfl_xor(A[i], off);
                #pragma unroll
                for (int p = 0; p < NP; ++p) Bv[p] += __shfl_xor(Bv[p], off);
            }

            // d = sum_{i<j} corr_ij, fp32 epilogue (all lanes redundantly)
            {
                const float Cf = (float)CDIM;
                const int diag[NM] = {0, 5, 9, 12, 14};
                float rden[NM];
                #pragma unroll
                for (int i = 0; i < NM; ++i)
                    rden[i] = rsqrtf(fmaf(Cf, Bv[diag[i]], -A[i] * A[i]));

                float d = 0.0f;
                int p = 0;
                #pragma unroll
                for (int i = 0; i < NM; ++i) {
                    #pragma unroll
                    for (int j = i; j < NM; ++j) {
                        if (j > i)
                            d += fmaf(Cf, Bv[p], -A[i] * A[j]) * rden[i] * rden[j];
                        ++p;
                    }
                }
                dsum += SCALEF * d;
            }

            #pragma unroll
            for (int m = 0; m < NM; ++m) rp[m] += CDIM;
        }
    }

    // per-block partial (fixed order): 4 waves -> 1 float
    if (lane == 0) sm4[wid] = dsum;
    __syncthreads();
    if (threadIdx.x == 0)
        ws[blockIdx.x] = (sm4[0] + sm4[1]) + (sm4[2] + sm4[3]);
}

// Deterministic fixed-order reduction of nblk block partials -> mean over B.
__global__ __launch_bounds__(256) void final_reduce(
    const float* __restrict__ ws, float* __restrict__ out, int nblk, int B)
{
    __shared__ double sm[256];
    double acc = 0.0;
    for (int i = threadIdx.x; i < nblk; i += 256)
        acc += (double)ws[i];
    sm[threadIdx.x] = acc;
    __syncthreads();
    #pragma unroll
    for (int s = 128; s > 0; s >>= 1) {
        if (threadIdx.x < s) sm[threadIdx.x] += sm[threadIdx.x + s];
        __syncthreads();
    }
    if (threadIdx.x == 0)
        out[0] = (float)(sm[0] / (double)B);
}

extern "C" void kernel_launch(void* const* d_in, const int* in_sizes, int n_in,
                              void* d_out, int out_size, void* d_ws, size_t ws_size,
                              hipStream_t stream)
{
    const float* o1 = (const float*)d_in[0];
    const float* o2 = (const float*)d_in[1];
    const float* o3 = (const float*)d_in[2];
    const float* o4 = (const float*)d_in[3];
    const float* o5 = (const float*)d_in[4];
    // d_in[5] (targets) unused by the reference.

    float* ws  = (float*)d_ws;
    float* out = (float*)d_out;

    const int B = in_sizes[0] / CDIM;                 // 16384
    const int waves  = (B + ROWS - 1) / ROWS;         // 4096
    const int blocks = (waves + 3) / 4;               // 1024

    diversity_rows<<<blocks, 256, 0, stream>>>(o1, o2, o3, o4, o5, ws, B);
    final_reduce<<<1, 256, 0, stream>>>(ws, out, blocks, B);
}